// Round 4
// baseline (388.756 us; speedup 1.0000x reference)
//
#include <hip/hip_runtime.h>
#include <math.h>

#define BB 8192
#define DIN 1024
#define DZ 256
#define DH 256
#define DT 16
#define DREC 256

// d_out layout (floats): I_hat, z, h, z_hat, spatial, temporal, energy
#define OFF_IHAT 0
#define OFF_Z    (BB * DIN)
#define OFF_H    (OFF_Z + BB * DZ)
#define OFF_ZHAT (OFF_H + BB * DH)
#define OFF_SCAL (OFF_ZHAT + BB * DZ)

// ---- workspace layout (u16 element offsets) -------------------------------
#define WS_HBF   0
#define WS_ZM1   2097152
#define WS_W     4194304
#define W_PM  (WS_W + 0)
#define W_PL  (W_PM + 262144)
#define W_Z2H (W_PL + 262144)
#define W_H2H (W_Z2H + 65536)
#define W_PRM (W_H2H + 65536)
#define W_PRL (W_PRM + 65536)
#define W_I2T (W_PRL + 65536)      // pre-scaled by 0.1
#define W_VIP (W_I2T + 16384)      // stored as -relu(W)
#define W_R1  (W_VIP + 4096)
#define W_R2  (W_R1 + 65536)
#define WS_END_W (W_R2 + 262144)   // 5328896
#define WS_SIGMA (WS_END_W + 262144)  // after theta fp32 (131072 f = 262144 u16)
#define WS_ZBF   (WS_SIGMA + 2097152)
#define WS_R1BF  (WS_ZBF + 2097152)

typedef unsigned short u16;
typedef __attribute__((ext_vector_type(8))) unsigned short u16x8;
typedef __attribute__((ext_vector_type(8))) __bf16 bf16x8;
typedef __attribute__((ext_vector_type(4))) float f32x4;

#define MFMA __builtin_amdgcn_mfma_f32_16x16x32_bf16

__device__ inline u16 f2bf(float f) {
  unsigned u = __builtin_bit_cast(unsigned, f);
  u += 0x7fff + ((u >> 16) & 1);
  return (u16)(u >> 16);
}
__device__ inline float bf2f(u16 v) {
  unsigned u = ((unsigned)v) << 16;
  return __builtin_bit_cast(float, u);
}
__device__ inline float softplus_stable(float y) {  // log(1+e^y)
  return (y > 20.f) ? y : log1pf(expf(y));
}
__device__ inline bf16x8 gf(const u16* p) {
  return __builtin_bit_cast(bf16x8, *(const u16x8*)p);
}
__device__ inline f32x4 fzero() { return (f32x4){0.f, 0.f, 0.f, 0.f}; }

__device__ inline float block_sum256(float v, float* rbuf) {
#pragma unroll
  for (int off = 32; off > 0; off >>= 1) v += __shfl_down(v, off, 64);
  __syncthreads();
  if ((threadIdx.x & 63) == 0) rbuf[threadIdx.x >> 6] = v;
  __syncthreads();
  return rbuf[0] + rbuf[1] + rbuf[2] + rbuf[3];
}

// ---------------------------------------------------------------------------
// k_cvt: fp32 -> bf16 for all GEMM operands, with folded scalings.
// ---------------------------------------------------------------------------
__global__ __launch_bounds__(256) void k_cvt(
    const float* __restrict__ I_t, const float* __restrict__ h_m_1,
    const float* __restrict__ z_m_1, const float* __restrict__ Wpm,
    const float* __restrict__ Wpl, const float* __restrict__ Wz2h,
    const float* __restrict__ Wh2h, const float* __restrict__ Wprm,
    const float* __restrict__ Wprl, const float* __restrict__ Wi2t,
    const float* __restrict__ Wv, const float* __restrict__ Wr1,
    const float* __restrict__ Wr2, u16* __restrict__ dstI,
    u16* __restrict__ dstW) {
  const int S1 = 8388608, S2 = 10485760, S3 = 12582912, S4 = 12845056,
            S5 = 13107200, S6 = 13172736, S7 = 13238272, S8 = 13303808,
            S9 = 13369344, S10 = 13385728, S11 = 13389824, S12 = 13455360,
            S13 = 13717504;
  int nchunk = S13 / 8;
  for (int c = blockIdx.x * 256 + threadIdx.x; c < nchunk;
       c += gridDim.x * 256) {
    int f = c * 8;
    const float* src;
    float scale = 1.f;
    bool nrelu = false;
    u16* dst;
    if (f < S1) {
      src = I_t + f;
      dst = dstI + f;
    } else {
      dst = dstW + (f - S1);
      if (f < S2)       src = h_m_1 + (f - S1);
      else if (f < S3)  src = z_m_1 + (f - S2);
      else if (f < S4)  src = Wpm + (f - S3);
      else if (f < S5)  src = Wpl + (f - S4);
      else if (f < S6)  src = Wz2h + (f - S5);
      else if (f < S7)  src = Wh2h + (f - S6);
      else if (f < S8)  src = Wprm + (f - S7);
      else if (f < S9)  src = Wprl + (f - S8);
      else if (f < S10) { src = Wi2t + (f - S9);  scale = 0.1f; }
      else if (f < S11) { src = Wv + (f - S10);   nrelu = true; }
      else if (f < S12) src = Wr1 + (f - S11);
      else              src = Wr2 + (f - S12);
    }
    float4 v0 = *(const float4*)(src);
    float4 v1 = *(const float4*)(src + 4);
    float vals[8] = {v0.x, v0.y, v0.z, v0.w, v1.x, v1.y, v1.z, v1.w};
    u16x8 o;
#pragma unroll
    for (int j = 0; j < 8; ++j) {
      float x = vals[j];
      x = nrelu ? -fmaxf(x, 0.f) : x * scale;
      o[j] = f2bf(x);
    }
    *(u16x8*)(dst) = o;
  }
}

// ---------------------------------------------------------------------------
// k_hp: h = relu(zm1@Wz2h^T + h@Wh2h^T); sigma_p = softplus_b(h@Wprl^T)/1.2;
//       z_hat = relu(h@Wprm^T) + eps_zhat*sigma_p; sigma -> bf16 ws.
// LDS-free direct-fragment GEMM. Tile 64 rows x 32 cols, grid (8,128)=1024.
// ---------------------------------------------------------------------------
__global__ __launch_bounds__(256, 2) void k_hp(
    const u16* __restrict__ h_bf, const u16* __restrict__ zm1,
    const u16* __restrict__ Wh2h, const u16* __restrict__ Wprm,
    const u16* __restrict__ Wprl, const u16* __restrict__ Wz2h,
    const float* __restrict__ eps_zhat, float* __restrict__ h_out,
    float* __restrict__ zhat_out, u16* __restrict__ sigma_bf) {
  const int tid = threadIdx.x, lane = tid & 63, w = tid >> 6;
  const int frow = lane & 15, fq = lane >> 4;
  const int row0 = blockIdx.y * 64, col0 = blockIdx.x * 32;
  f32x4 ah[2], am[2], as_[2];
#pragma unroll
  for (int i = 0; i < 2; ++i) { ah[i] = fzero(); am[i] = fzero(); as_[i] = fzero(); }

  const u16* Ap  = h_bf + (size_t)(row0 + w * 16 + frow) * DH + fq * 8;
  const u16* Bh0 = Wh2h + (size_t)(col0 + frow) * DH + fq * 8;
  const u16* Bh1 = Bh0 + 16 * DH;
  const u16* Bm0 = Wprm + (size_t)(col0 + frow) * DH + fq * 8;
  const u16* Bm1 = Bm0 + 16 * DH;
  const u16* Bs0 = Wprl + (size_t)(col0 + frow) * DH + fq * 8;
  const u16* Bs1 = Bs0 + 16 * DH;
#pragma unroll 4
  for (int k = 0; k < DH; k += 32) {
    bf16x8 a = gf(Ap + k);
    ah[0]  = MFMA(a, gf(Bh0 + k), ah[0], 0, 0, 0);
    ah[1]  = MFMA(a, gf(Bh1 + k), ah[1], 0, 0, 0);
    am[0]  = MFMA(a, gf(Bm0 + k), am[0], 0, 0, 0);
    am[1]  = MFMA(a, gf(Bm1 + k), am[1], 0, 0, 0);
    as_[0] = MFMA(a, gf(Bs0 + k), as_[0], 0, 0, 0);
    as_[1] = MFMA(a, gf(Bs1 + k), as_[1], 0, 0, 0);
  }
  const u16* Ap2 = zm1 + (size_t)(row0 + w * 16 + frow) * DZ + fq * 8;
  const u16* Bz0 = Wz2h + (size_t)(col0 + frow) * DZ + fq * 8;
  const u16* Bz1 = Bz0 + 16 * DZ;
#pragma unroll 4
  for (int k = 0; k < DZ; k += 32) {
    bf16x8 a = gf(Ap2 + k);
    ah[0] = MFMA(a, gf(Bz0 + k), ah[0], 0, 0, 0);
    ah[1] = MFMA(a, gf(Bz1 + k), ah[1], 0, 0, 0);
  }
#pragma unroll
  for (int ni = 0; ni < 2; ++ni)
#pragma unroll
    for (int r = 0; r < 4; ++r) {
      int m = row0 + w * 16 + fq * 4 + r;
      int n = col0 + ni * 16 + frow;
      h_out[(size_t)m * DH + n] = fmaxf(ah[ni][r], 0.f);
      float sig = softplus_stable(1.2f * as_[ni][r]) * (1.f / 1.2f);
      float mu = fmaxf(am[ni][r], 0.f);
      zhat_out[(size_t)m * DZ + n] = mu + eps_zhat[(size_t)m * DZ + n] * sig;
      sigma_bf[(size_t)m * DZ + n] = f2bf(sig);
    }
}

// ---------------------------------------------------------------------------
// k_post: mu_q/sigma_q dual GEMM (K=1024) + theta GEMM on same A-frags,
// + sigma@(-relu(Wv)) pass, + fused z epilogue and temporal/energy losses.
// Tile 64 x 32, grid (8,128)=1024.
// ---------------------------------------------------------------------------
__global__ __launch_bounds__(256, 2) void k_post(
    const u16* __restrict__ I_bf, const u16* __restrict__ Wpm,
    const u16* __restrict__ Wpl, const u16* __restrict__ Wi2t,
    const u16* __restrict__ Wv, const u16* __restrict__ sigma_bf,
    const float* __restrict__ theta_m_1, const float* __restrict__ W_t2z,
    const float* __restrict__ eps_z, const float* __restrict__ zhat,
    float* __restrict__ z_out, u16* __restrict__ z_bf,
    float* __restrict__ scal) {
  __shared__ float th_s[64 * 17];
  __shared__ float wt_s[32 * 17];
  __shared__ float rbuf[4];
  const int tid = threadIdx.x, lane = tid & 63, w = tid >> 6;
  const int frow = lane & 15, fq = lane >> 4;
  const int row0 = blockIdx.y * 64, col0 = blockIdx.x * 32;
  f32x4 accm[2], accs[2], acct = fzero();
#pragma unroll
  for (int i = 0; i < 2; ++i) { accm[i] = fzero(); accs[i] = fzero(); }

  const u16* Ap  = I_bf + (size_t)(row0 + w * 16 + frow) * DIN + fq * 8;
  const u16* Bm0 = Wpm + (size_t)(col0 + frow) * DIN + fq * 8;
  const u16* Bm1 = Bm0 + 16 * DIN;
  const u16* Bs0 = Wpl + (size_t)(col0 + frow) * DIN + fq * 8;
  const u16* Bs1 = Bs0 + 16 * DIN;
  const u16* Bt  = Wi2t + (size_t)frow * DIN + fq * 8;
#pragma unroll 4
  for (int k = 0; k < DIN; k += 32) {
    bf16x8 a = gf(Ap + k);
    accm[0] = MFMA(a, gf(Bm0 + k), accm[0], 0, 0, 0);
    accm[1] = MFMA(a, gf(Bm1 + k), accm[1], 0, 0, 0);
    accs[0] = MFMA(a, gf(Bs0 + k), accs[0], 0, 0, 0);
    accs[1] = MFMA(a, gf(Bs1 + k), accs[1], 0, 0, 0);
    acct    = MFMA(a, gf(Bt + k), acct, 0, 0, 0);
  }
  const u16* Ap2 = sigma_bf + (size_t)(row0 + w * 16 + frow) * DZ + fq * 8;
  const u16* Bt2 = Wv + (size_t)frow * DZ + fq * 8;
#pragma unroll 4
  for (int k = 0; k < DZ; k += 32)
    acct = MFMA(gf(Ap2 + k), gf(Bt2 + k), acct, 0, 0, 0);

  // finalize theta (rows of this block), broadcast via LDS
#pragma unroll
  for (int r = 0; r < 4; ++r) {
    int lr = w * 16 + fq * 4 + r;
    float th = 0.5f * theta_m_1[(size_t)(row0 + lr) * DT + frow] + acct[r];
    th_s[lr * 17 + frow] = 0.002f * softplus_stable(0.5f * th);
  }
  if (tid < 512) {
#pragma unroll
    for (int i = 0; i < 2; ++i) {
      int idx = tid + 256 * i;
      if (idx < 32 * 16) {
        int n = idx >> 4, j = idx & 15;
        wt_s[n * 17 + j] = 10.f * fmaxf(W_t2z[(col0 + n) * DT + j], 0.f);
      }
    }
  }
  __syncthreads();

  float tsum = 0.f, esum = 0.f;
#pragma unroll
  for (int ni = 0; ni < 2; ++ni)
#pragma unroll
    for (int r = 0; r < 4; ++r) {
      int lr = w * 16 + fq * 4 + r;
      int ln = ni * 16 + frow;
      int m = row0 + lr;
      int n = col0 + ln;
      float mu = fmaxf(accm[ni][r], 0.f);
      float sq = fmaxf(accs[ni][r], 0.f);
      float raw = mu + eps_z[(size_t)m * DZ + n] * sq;
      raw = fminf(fmaxf(raw, 0.f), 1.f);
      float thr = 0.f;
#pragma unroll
      for (int j = 0; j < 16; ++j)
        thr = fmaf(th_s[lr * 17 + j], wt_s[ln * 17 + j], thr);
      float zz = fmaxf(raw - thr, 0.f);
      z_out[(size_t)m * DZ + n] = zz;
      z_bf[(size_t)m * DZ + n] = f2bf(zz);
      float d = zz - zhat[(size_t)m * DZ + n];
      tsum += d * d;
      esum += zz;
    }
  float t = block_sum256(tsum, rbuf);
  if (tid == 0) atomicAdd(scal + 1, t * (1.f / ((float)BB * DZ)));
  float e = block_sum256(esum, rbuf);
  if (tid == 0) atomicAdd(scal + 2, e * (1.f / ((float)BB * DZ)));
}

// ---------------------------------------------------------------------------
// k_rec1: r1 = z @ Wr1^T -> bf16.  Tile 64x32, grid (8,128)=1024.
// ---------------------------------------------------------------------------
__global__ __launch_bounds__(256, 2) void k_rec1(const u16* __restrict__ z_bf,
                                                 const u16* __restrict__ Wr1,
                                                 u16* __restrict__ r1_bf) {
  const int tid = threadIdx.x, lane = tid & 63, w = tid >> 6;
  const int frow = lane & 15, fq = lane >> 4;
  const int row0 = blockIdx.y * 64, col0 = blockIdx.x * 32;
  f32x4 acc[2] = {fzero(), fzero()};
  const u16* Ap = z_bf + (size_t)(row0 + w * 16 + frow) * DZ + fq * 8;
  const u16* B0 = Wr1 + (size_t)(col0 + frow) * DZ + fq * 8;
  const u16* B1 = B0 + 16 * DZ;
#pragma unroll 4
  for (int k = 0; k < DZ; k += 32) {
    bf16x8 a = gf(Ap + k);
    acc[0] = MFMA(a, gf(B0 + k), acc[0], 0, 0, 0);
    acc[1] = MFMA(a, gf(B1 + k), acc[1], 0, 0, 0);
  }
#pragma unroll
  for (int ni = 0; ni < 2; ++ni)
#pragma unroll
    for (int r = 0; r < 4; ++r) {
      int m = row0 + w * 16 + fq * 4 + r;
      int n = col0 + ni * 16 + frow;
      r1_bf[(size_t)m * DREC + n] = f2bf(acc[ni][r]);
    }
}

// ---------------------------------------------------------------------------
// k_rec2: I_hat = sigmoid(r1 @ Wr2^T) + fused spatial loss.
// Tile 64x64, grid (16,128)=2048.
// ---------------------------------------------------------------------------
__global__ __launch_bounds__(256, 2) void k_rec2(const u16* __restrict__ r1_bf,
                                                 const u16* __restrict__ Wr2,
                                                 const float* __restrict__ I_t,
                                                 float* __restrict__ ihat_out,
                                                 float* __restrict__ scal) {
  __shared__ float rbuf[4];
  const int tid = threadIdx.x, lane = tid & 63, w = tid >> 6;
  const int frow = lane & 15, fq = lane >> 4;
  const int row0 = blockIdx.y * 64, col0 = blockIdx.x * 64;
  f32x4 acc[4] = {fzero(), fzero(), fzero(), fzero()};
  const u16* Ap = r1_bf + (size_t)(row0 + w * 16 + frow) * DREC + fq * 8;
  const u16* B0 = Wr2 + (size_t)(col0 + frow) * DREC + fq * 8;
#pragma unroll 4
  for (int k = 0; k < DREC; k += 32) {
    bf16x8 a = gf(Ap + k);
#pragma unroll
    for (int ni = 0; ni < 4; ++ni)
      acc[ni] = MFMA(a, gf(B0 + ni * 16 * DREC + k), acc[ni], 0, 0, 0);
  }
  float lsum = 0.f;
#pragma unroll
  for (int ni = 0; ni < 4; ++ni)
#pragma unroll
    for (int r = 0; r < 4; ++r) {
      int m = row0 + w * 16 + fq * 4 + r;
      int n = col0 + ni * 16 + frow;
      float ih = 1.f / (1.f + expf(-acc[ni][r]));
      ihat_out[(size_t)m * DIN + n] = ih;
      float d = I_t[(size_t)m * DIN + n] - ih;
      lsum += d * d;
    }
  float s = block_sum256(lsum, rbuf);
  if (tid == 0) atomicAdd(scal + 0, s * (1.f / ((float)BB * DIN)));
}

// ---------------------------------------------------------------------------
extern "C" void kernel_launch(void* const* d_in, const int* in_sizes, int n_in,
                              void* d_out, int out_size, void* d_ws,
                              size_t ws_size, hipStream_t stream) {
  const float* I_t       = (const float*)d_in[0];
  const float* h_m_1     = (const float*)d_in[1];
  const float* z_m_1     = (const float*)d_in[2];
  const float* theta_m_1 = (const float*)d_in[3];
  const float* eps_z     = (const float*)d_in[4];
  const float* eps_zhat  = (const float*)d_in[5];
  const float* W_post_mu = (const float*)d_in[6];
  const float* W_post_lv = (const float*)d_in[7];
  const float* W_z2h     = (const float*)d_in[8];
  const float* W_h2h     = (const float*)d_in[9];
  const float* W_prior_mu= (const float*)d_in[10];
  const float* W_prior_lv= (const float*)d_in[11];
  const float* W_i2t     = (const float*)d_in[12];
  const float* W_vip2t   = (const float*)d_in[13];
  const float* W_t2z     = (const float*)d_in[14];
  const float* W_rec1    = (const float*)d_in[15];
  const float* W_rec2    = (const float*)d_in[16];

  float* out = (float*)d_out;
  float* ihat = out + OFF_IHAT;
  float* zout = out + OFF_Z;
  float* hout = out + OFF_H;
  float* zhat = out + OFF_ZHAT;
  float* scal = out + OFF_SCAL;

  u16* ws_u = (u16*)d_ws;
  u16* I_bf = (u16*)ihat;  // scratch inside d_out, dead before k_rec2 writes
  u16* h_bf = ws_u + WS_HBF;
  u16* zm1_bf = ws_u + WS_ZM1;
  float* theta_ws = (float*)(ws_u + WS_END_W);
  u16* sigma_bf = ws_u + WS_SIGMA;
  u16* z_bf = ws_u + WS_ZBF;
  u16* r1_bf = ws_u + WS_R1BF;
  (void)theta_ws;

  hipMemsetAsync(scal, 0, 3 * sizeof(float), stream);

  k_cvt<<<2048, 256, 0, stream>>>(I_t, h_m_1, z_m_1, W_post_mu, W_post_lv,
                                  W_z2h, W_h2h, W_prior_mu, W_prior_lv, W_i2t,
                                  W_vip2t, W_rec1, W_rec2, I_bf, ws_u + WS_HBF);

  dim3 g32(DZ / 32, BB / 64);    // 8 x 128 = 1024
  dim3 g64(DIN / 64, BB / 64);   // 16 x 128 = 2048

  k_hp<<<g32, 256, 0, stream>>>(h_bf, zm1_bf, ws_u + W_H2H, ws_u + W_PRM,
                                ws_u + W_PRL, ws_u + W_Z2H, eps_zhat, hout,
                                zhat, sigma_bf);
  k_post<<<g32, 256, 0, stream>>>(I_bf, ws_u + W_PM, ws_u + W_PL, ws_u + W_I2T,
                                  ws_u + W_VIP, sigma_bf, theta_m_1, W_t2z,
                                  eps_z, zhat, zout, z_bf, scal);
  k_rec1<<<g32, 256, 0, stream>>>(z_bf, ws_u + W_R1, r1_bf);
  k_rec2<<<g64, 256, 0, stream>>>(r1_bf, ws_u + W_R2, I_t, ihat, scal);
}

// Round 5
// 314.583 us; speedup vs baseline: 1.2358x; 1.2358x over previous
//
#include <hip/hip_runtime.h>
#include <math.h>

#define BB 8192
#define DIN 1024
#define DZ 256
#define DH 256
#define DT 16
#define DREC 256

// d_out layout (floats): I_hat, z, h, z_hat, spatial, temporal, energy
#define OFF_IHAT 0
#define OFF_Z    (BB * DIN)
#define OFF_H    (OFF_Z + BB * DZ)
#define OFF_ZHAT (OFF_H + BB * DH)
#define OFF_SCAL (OFF_ZHAT + BB * DZ)

// bf16 weight pack offsets (u16 elements) in d_ws
#define WB_PM  0
#define WB_PL  262144
#define WB_Z2H 524288
#define WB_H2H 589824
#define WB_PRM 655360
#define WB_PRL 720896
#define WB_I2T 786432   // pre-scaled by 0.1
#define WB_VIP 802816   // stored as -relu(W)
#define WB_R1  806912
#define WB_R2  872448
#define WB_END 1134592

#define STRD 264  // LDS row stride in u16 (16 rows x 256 k + 8 pad)

typedef unsigned short u16;
typedef __attribute__((ext_vector_type(8))) unsigned short u16x8;
typedef __attribute__((ext_vector_type(8))) __bf16 bf16x8;
typedef __attribute__((ext_vector_type(4))) float f32x4;

#define MFMA __builtin_amdgcn_mfma_f32_16x16x32_bf16

__device__ inline u16 f2bf(float f) {
  unsigned u = __builtin_bit_cast(unsigned, f);
  u += 0x7fff + ((u >> 16) & 1);
  return (u16)(u >> 16);
}
__device__ inline float softplus_stable(float y) {  // log(1+e^y)
  return (y > 20.f) ? y : log1pf(expf(y));
}
__device__ inline bf16x8 gf(const u16* p) {
  return __builtin_bit_cast(bf16x8, *(const u16x8*)p);
}
__device__ inline f32x4 fzero() { return (f32x4){0.f, 0.f, 0.f, 0.f}; }

__device__ inline float block_sum256(float v, float* rbuf) {
#pragma unroll
  for (int off = 32; off > 0; off >>= 1) v += __shfl_down(v, off, 64);
  __syncthreads();  // also protects rbuf against back-to-back reuse
  if ((threadIdx.x & 63) == 0) rbuf[threadIdx.x >> 6] = v;
  __syncthreads();
  return rbuf[0] + rbuf[1] + rbuf[2] + rbuf[3];
}

// load 16 rows x 256 k fp32 chunk into regs (4 float4/thread)
__device__ inline void ldA(float4 (&v)[4], const float* __restrict__ src,
                           int row0, int ld, int k0) {
  const int r = threadIdx.x & 15, cg = threadIdx.x >> 4;
  const float* p = src + (size_t)(row0 + r) * ld + k0 + cg * 16;
  v[0] = ((const float4*)p)[0];
  v[1] = ((const float4*)p)[1];
  v[2] = ((const float4*)p)[2];
  v[3] = ((const float4*)p)[3];
}
// convert + store the chunk to LDS (bf16)
__device__ inline void stA(u16* lds, const float4 (&v)[4]) {
  const int r = threadIdx.x & 15, cg = threadIdx.x >> 4;
  float a[8] = {v[0].x, v[0].y, v[0].z, v[0].w, v[1].x, v[1].y, v[1].z, v[1].w};
  float b[8] = {v[2].x, v[2].y, v[2].z, v[2].w, v[3].x, v[3].y, v[3].z, v[3].w};
  u16x8 lo, hi;
#pragma unroll
  for (int j = 0; j < 8; ++j) { lo[j] = f2bf(a[j]); hi[j] = f2bf(b[j]); }
  *(u16x8*)(lds + r * STRD + cg * 16) = lo;
  *(u16x8*)(lds + r * STRD + cg * 16 + 8) = hi;
}

// ---------------------------------------------------------------------------
// k_cvtw: weights fp32 -> bf16 (0.1*Wi2t, -relu(Wvip2t) folded)
// ---------------------------------------------------------------------------
__global__ __launch_bounds__(256) void k_cvtw(
    const float* __restrict__ Wpm, const float* __restrict__ Wpl,
    const float* __restrict__ Wz2h, const float* __restrict__ Wh2h,
    const float* __restrict__ Wprm, const float* __restrict__ Wprl,
    const float* __restrict__ Wi2t, const float* __restrict__ Wv,
    const float* __restrict__ Wr1, const float* __restrict__ Wr2,
    u16* __restrict__ dst) {
  const int NT = WB_END / 8;
  for (int c = blockIdx.x * 256 + threadIdx.x; c < NT; c += gridDim.x * 256) {
    int f = c * 8;
    const float* src;
    float scale = 1.f;
    bool nrelu = false;
    if (f < WB_PL)        src = Wpm + f;
    else if (f < WB_Z2H)  src = Wpl + (f - WB_PL);
    else if (f < WB_H2H)  src = Wz2h + (f - WB_Z2H);
    else if (f < WB_PRM)  src = Wh2h + (f - WB_H2H);
    else if (f < WB_PRL)  src = Wprm + (f - WB_PRM);
    else if (f < WB_I2T)  src = Wprl + (f - WB_PRL);
    else if (f < WB_VIP)  { src = Wi2t + (f - WB_I2T); scale = 0.1f; }
    else if (f < WB_R1)   { src = Wv + (f - WB_VIP); nrelu = true; }
    else if (f < WB_R2)   src = Wr1 + (f - WB_R1);
    else                  src = Wr2 + (f - WB_R2);
    float4 v0 = *(const float4*)(src);
    float4 v1 = *(const float4*)(src + 4);
    float vals[8] = {v0.x, v0.y, v0.z, v0.w, v1.x, v1.y, v1.z, v1.w};
    u16x8 o;
#pragma unroll
    for (int j = 0; j < 8; ++j) {
      float x = vals[j];
      x = nrelu ? -fmaxf(x, 0.f) : x * scale;
      o[j] = f2bf(x);
    }
    *(u16x8*)(dst + f) = o;
  }
}

// ---------------------------------------------------------------------------
// k_mega: entire model for a 16-row strip. Grid 512 x 256 threads.
// Wave w owns cols [w*64,(w+1)*64) for N=256 phases, [w*256,(w+1)*256) for rec2.
// ---------------------------------------------------------------------------
__global__ __launch_bounds__(256, 2) void k_mega(
    const float* __restrict__ I_t, const float* __restrict__ h_m_1,
    const float* __restrict__ z_m_1, const float* __restrict__ theta_m_1,
    const float* __restrict__ eps_z, const float* __restrict__ eps_zhat,
    const float* __restrict__ W_t2z, const u16* __restrict__ Wb,
    float* __restrict__ ihat, float* __restrict__ zout,
    float* __restrict__ hout, float* __restrict__ zhatout,
    float* __restrict__ scal) {
  __shared__ __align__(16) u16 A_lds[16 * STRD];
  __shared__ __align__(16) u16 B_lds[16 * STRD];
  __shared__ float th_s[16 * 17];
  __shared__ float wt_s[256 * 17];
  __shared__ float rbuf[4];

  const int tid = threadIdx.x, lane = tid & 63, w = tid >> 6;
  const int frow = lane & 15, fq = lane >> 4;
  const int row0 = blockIdx.x * 16;

  const u16* Wpm  = Wb + WB_PM;
  const u16* Wpl  = Wb + WB_PL;
  const u16* Wz2h = Wb + WB_Z2H;
  const u16* Wh2h = Wb + WB_H2H;
  const u16* Wprm = Wb + WB_PRM;
  const u16* Wprl = Wb + WB_PRL;
  const u16* Wi2t = Wb + WB_I2T;
  const u16* Wv   = Wb + WB_VIP;
  const u16* Wr1  = Wb + WB_R1;
  const u16* Wr2  = Wb + WB_R2;

  float4 pre[4];
  // ---- phase 1: A = h_m_1 (K=256): h, mu_p, sigma_p GEMMs -----------------
  ldA(pre, h_m_1, row0, DH, 0);
  stA(A_lds, pre);
  __syncthreads();
  ldA(pre, z_m_1, row0, DZ, 0);  // prefetch zm1 during h-pass

  f32x4 ah[4], am[4], as_[4];
#pragma unroll
  for (int i = 0; i < 4; ++i) { ah[i] = fzero(); am[i] = fzero(); as_[i] = fzero(); }
  {
    const u16* pA = A_lds + frow * STRD + fq * 8;
    const u16* pH = Wh2h + (size_t)(w * 64 + frow) * DH + fq * 8;
    const u16* pM = Wprm + (size_t)(w * 64 + frow) * DH + fq * 8;
    const u16* pS = Wprl + (size_t)(w * 64 + frow) * DH + fq * 8;
#pragma unroll 4
    for (int ks = 0; ks < 8; ++ks) {
      bf16x8 a = gf(pA + ks * 32);
#pragma unroll
      for (int ni = 0; ni < 4; ++ni) {
        ah[ni]  = MFMA(a, gf(pH + ni * 16 * DH + ks * 32), ah[ni], 0, 0, 0);
        am[ni]  = MFMA(a, gf(pM + ni * 16 * DH + ks * 32), am[ni], 0, 0, 0);
        as_[ni] = MFMA(a, gf(pS + ni * 16 * DH + ks * 32), as_[ni], 0, 0, 0);
      }
    }
  }
  __syncthreads();
  stA(A_lds, pre);  // zm1
  __syncthreads();
  ldA(pre, I_t, row0, DIN, 0);  // prefetch I chunk0

  // ---- phase 2: A = z_m_1 (K=256): h += z@Wz2h ----------------------------
  {
    const u16* pA = A_lds + frow * STRD + fq * 8;
    const u16* pZ = Wz2h + (size_t)(w * 64 + frow) * DZ + fq * 8;
#pragma unroll 4
    for (int ks = 0; ks < 8; ++ks) {
      bf16x8 a = gf(pA + ks * 32);
#pragma unroll
      for (int ni = 0; ni < 4; ++ni)
        ah[ni] = MFMA(a, gf(pZ + ni * 16 * DZ + ks * 32), ah[ni], 0, 0, 0);
    }
  }
  // ---- epilogue 1: h, sigma_p (->B_lds), z_hat (kept in regs) -------------
  f32x4 zh[4];
#pragma unroll
  for (int ni = 0; ni < 4; ++ni)
#pragma unroll
    for (int r = 0; r < 4; ++r) {
      int m = row0 + fq * 4 + r;
      int n = w * 64 + ni * 16 + frow;
      hout[(size_t)m * DH + n] = fmaxf(ah[ni][r], 0.f);
      float sig = softplus_stable(1.2f * as_[ni][r]) * (1.f / 1.2f);
      float mu = fmaxf(am[ni][r], 0.f);
      float z = mu + eps_zhat[(size_t)m * DZ + n] * sig;
      zh[ni][r] = z;
      zhatout[(size_t)m * DZ + n] = z;
      B_lds[(fq * 4 + r) * STRD + n] = f2bf(sig);
    }
  __syncthreads();  // zm1 reads done; sigma visible
  stA(A_lds, pre);  // I chunk0 -> LDS
  ldA(pre, I_t, row0, DIN, 256);  // prefetch chunk1

  // ---- phase 3: theta sigma-part: acct += sigma @ (-relu(Wv))^T -----------
  f32x4 acct = fzero();
  {
    const u16* pA = B_lds + frow * STRD + fq * 8;
    const u16* pV = Wv + (size_t)frow * DZ + fq * 8;
#pragma unroll 4
    for (int ks = 0; ks < 8; ++ks)
      acct = MFMA(gf(pA + ks * 32), gf(pV + ks * 32), acct, 0, 0, 0);
  }
  __syncthreads();  // chunk0 staged; B_lds reads done

  // ---- phase 4: A = I (K=1024): mu_q, sigma_q, theta I-part ---------------
  f32x4 accm[4], accs[4];
#pragma unroll
  for (int i = 0; i < 4; ++i) { accm[i] = fzero(); accs[i] = fzero(); }
  {
    const u16* pA = A_lds + frow * STRD + fq * 8;
    const u16* pM = Wpm + (size_t)(w * 64 + frow) * DIN + fq * 8;
    const u16* pS = Wpl + (size_t)(w * 64 + frow) * DIN + fq * 8;
    const u16* pT = Wi2t + (size_t)frow * DIN + fq * 8;
#pragma unroll 1
    for (int c = 0; c < 4; ++c) {
      int kb = c * 256;
#pragma unroll 4
      for (int ks = 0; ks < 8; ++ks) {
        bf16x8 a = gf(pA + ks * 32);
#pragma unroll
        for (int ni = 0; ni < 4; ++ni) {
          accm[ni] = MFMA(a, gf(pM + ni * 16 * DIN + kb + ks * 32), accm[ni], 0, 0, 0);
          accs[ni] = MFMA(a, gf(pS + ni * 16 * DIN + kb + ks * 32), accs[ni], 0, 0, 0);
        }
        acct = MFMA(a, gf(pT + kb + ks * 32), acct, 0, 0, 0);
      }
      __syncthreads();
      if (c < 3) {
        stA(A_lds, pre);
        if (c < 2) ldA(pre, I_t, row0, DIN, (c + 2) * 256);
        __syncthreads();
      }
    }
  }
  // ---- theta finalize + threshold weights ---------------------------------
  if (w == 0) {
#pragma unroll
    for (int r = 0; r < 4; ++r) {
      int lr = fq * 4 + r;
      float th = 0.5f * theta_m_1[(size_t)(row0 + lr) * DT + frow] + acct[r];
      th_s[lr * 17 + frow] = 0.002f * softplus_stable(0.5f * th);
    }
  }
  {
    const float* p = W_t2z + tid * 16;  // 256 rows x 16
    float4 a0 = ((const float4*)p)[0], a1 = ((const float4*)p)[1];
    float4 a2 = ((const float4*)p)[2], a3 = ((const float4*)p)[3];
    float v[16] = {a0.x, a0.y, a0.z, a0.w, a1.x, a1.y, a1.z, a1.w,
                   a2.x, a2.y, a2.z, a2.w, a3.x, a3.y, a3.z, a3.w};
#pragma unroll
    for (int j = 0; j < 16; ++j) wt_s[tid * 17 + j] = 10.f * fmaxf(v[j], 0.f);
  }
  __syncthreads();

  // ---- z epilogue: z = relu(clip(mu+eps*sig,0,1) - th.wt), losses ---------
  float tsum = 0.f, esum = 0.f;
#pragma unroll
  for (int ni = 0; ni < 4; ++ni)
#pragma unroll
    for (int r = 0; r < 4; ++r) {
      int lr = fq * 4 + r;
      int ln = w * 64 + ni * 16 + frow;
      int m = row0 + lr;
      float mu = fmaxf(accm[ni][r], 0.f);
      float sq = fmaxf(accs[ni][r], 0.f);
      float raw = mu + eps_z[(size_t)m * DZ + ln] * sq;
      raw = fminf(fmaxf(raw, 0.f), 1.f);
      float thr = 0.f;
#pragma unroll
      for (int j = 0; j < 16; ++j)
        thr = fmaf(th_s[lr * 17 + j], wt_s[ln * 17 + j], thr);
      float zz = fmaxf(raw - thr, 0.f);
      zout[(size_t)m * DZ + ln] = zz;
      A_lds[lr * STRD + ln] = f2bf(zz);
      float d = zz - zh[ni][r];
      tsum += d * d;
      esum += zz;
    }
  float t = block_sum256(tsum, rbuf);
  if (tid == 0) atomicAdd(scal + 1, t * (1.f / ((float)BB * DZ)));
  float e = block_sum256(esum, rbuf);
  if (tid == 0) atomicAdd(scal + 2, e * (1.f / ((float)BB * DZ)));
  __syncthreads();

  // ---- rec1: r1 = z @ Wr1^T (A from LDS) ----------------------------------
  f32x4 ar[4];
#pragma unroll
  for (int i = 0; i < 4; ++i) ar[i] = fzero();
  {
    const u16* pA = A_lds + frow * STRD + fq * 8;
    const u16* pR = Wr1 + (size_t)(w * 64 + frow) * DZ + fq * 8;
#pragma unroll 4
    for (int ks = 0; ks < 8; ++ks) {
      bf16x8 a = gf(pA + ks * 32);
#pragma unroll
      for (int ni = 0; ni < 4; ++ni)
        ar[ni] = MFMA(a, gf(pR + ni * 16 * DZ + ks * 32), ar[ni], 0, 0, 0);
    }
  }
#pragma unroll
  for (int ni = 0; ni < 4; ++ni)
#pragma unroll
    for (int r = 0; r < 4; ++r)
      B_lds[(fq * 4 + r) * STRD + w * 64 + ni * 16 + frow] = f2bf(ar[ni][r]);
  __syncthreads();

  // ---- rec2: I_hat = sigmoid(r1 @ Wr2^T), spatial loss --------------------
  f32x4 ai[16];
#pragma unroll
  for (int i = 0; i < 16; ++i) ai[i] = fzero();
  {
    const u16* pA = B_lds + frow * STRD + fq * 8;
    const u16* pR = Wr2 + (size_t)(w * 256 + frow) * DREC + fq * 8;
#pragma unroll 2
    for (int ks = 0; ks < 8; ++ks) {
      bf16x8 a = gf(pA + ks * 32);
#pragma unroll
      for (int ni = 0; ni < 16; ++ni)
        ai[ni] = MFMA(a, gf(pR + ni * 16 * DREC + ks * 32), ai[ni], 0, 0, 0);
    }
  }
  float lsum = 0.f;
#pragma unroll
  for (int ni = 0; ni < 16; ++ni)
#pragma unroll
    for (int r = 0; r < 4; ++r) {
      int m = row0 + fq * 4 + r;
      int n = w * 256 + ni * 16 + frow;
      float ih = 1.f / (1.f + expf(-ai[ni][r]));
      ihat[(size_t)m * DIN + n] = ih;
      float d = I_t[(size_t)m * DIN + n] - ih;
      lsum += d * d;
    }
  float s = block_sum256(lsum, rbuf);
  if (tid == 0) atomicAdd(scal + 0, s * (1.f / ((float)BB * DIN)));
}

// ---------------------------------------------------------------------------
extern "C" void kernel_launch(void* const* d_in, const int* in_sizes, int n_in,
                              void* d_out, int out_size, void* d_ws,
                              size_t ws_size, hipStream_t stream) {
  const float* I_t       = (const float*)d_in[0];
  const float* h_m_1     = (const float*)d_in[1];
  const float* z_m_1     = (const float*)d_in[2];
  const float* theta_m_1 = (const float*)d_in[3];
  const float* eps_z     = (const float*)d_in[4];
  const float* eps_zhat  = (const float*)d_in[5];
  const float* W_post_mu = (const float*)d_in[6];
  const float* W_post_lv = (const float*)d_in[7];
  const float* W_z2h     = (const float*)d_in[8];
  const float* W_h2h     = (const float*)d_in[9];
  const float* W_prior_mu= (const float*)d_in[10];
  const float* W_prior_lv= (const float*)d_in[11];
  const float* W_i2t     = (const float*)d_in[12];
  const float* W_vip2t   = (const float*)d_in[13];
  const float* W_t2z     = (const float*)d_in[14];
  const float* W_rec1    = (const float*)d_in[15];
  const float* W_rec2    = (const float*)d_in[16];

  float* out = (float*)d_out;
  float* ihat = out + OFF_IHAT;
  float* zout = out + OFF_Z;
  float* hout = out + OFF_H;
  float* zhat = out + OFF_ZHAT;
  float* scal = out + OFF_SCAL;

  u16* Wb = (u16*)d_ws;

  hipMemsetAsync(scal, 0, 3 * sizeof(float), stream);

  k_cvtw<<<512, 256, 0, stream>>>(W_post_mu, W_post_lv, W_z2h, W_h2h,
                                  W_prior_mu, W_prior_lv, W_i2t, W_vip2t,
                                  W_rec1, W_rec2, Wb);
  k_mega<<<BB / 16, 256, 0, stream>>>(I_t, h_m_1, z_m_1, theta_m_1, eps_z,
                                      eps_zhat, W_t2z, Wb, ihat, zout, hout,
                                      zhat, scal);
}